// Round 4
// baseline (673.522 us; speedup 1.0000x reference)
//
#include <hip/hip_runtime.h>

// Problem constants (from reference): B=64, TOPK=2, E=16, C=1024, K=4096
#define BB    64
#define TOPK  2
#define EE    16
#define CC    1024
#define KK    4096

constexpr int RPB = 16;            // weight rows per block (4 per wave)
constexpr int P   = 4;             // (token,slot) pairs staged per pass
constexpr int KS  = 16;            // K-split (partial sums via atomics)
constexpr int KH  = KK / KS;       // floats per K-slice (=256)

typedef float v4f __attribute__((ext_vector_type(4)));

// ---------------------------------------------------------------------------
// Kernel 1: block 0 builds per-expert routing lists; other blocks initialize
//   out[b,c] = residual[b,c] + sum_s ew[b,s] * bias[idx[b,s], c]
// ---------------------------------------------------------------------------
__global__ __launch_bounds__(256) void route_init(
    const int* __restrict__ idx, const float* __restrict__ ew,
    const float* __restrict__ bias, const float* __restrict__ resid,
    float* __restrict__ out, int* __restrict__ cnt, int* __restrict__ lists)
{
    if (blockIdx.x == 0) {
        __shared__ int scnt[EE];
        if (threadIdx.x < EE) scnt[threadIdx.x] = 0;
        __syncthreads();
        if (threadIdx.x < BB * TOPK) {
            int e = idx[threadIdx.x];
            int pos = atomicAdd(&scnt[e], 1);
            lists[e * 128 + pos] = threadIdx.x;   // pair id = b*TOPK + slot
        }
        __syncthreads();
        if (threadIdx.x < EE) cnt[threadIdx.x] = scnt[threadIdx.x];
    } else {
        int i = (blockIdx.x - 1) * 256 + threadIdx.x;   // i in [0, B*C)
        int b = i >> 10;                                 // C = 1024
        int c = i & (CC - 1);
        float v = resid[i];
#pragma unroll
        for (int s = 0; s < TOPK; s++) {
            int e = idx[b * TOPK + s];
            v += ew[b * TOPK + s] * bias[e * CC + c];
        }
        out[i] = v;
    }
}

// ---------------------------------------------------------------------------
// Kernel 2: grid = E * 64 * KS = 16384 one-shot blocks, 256 threads.
//
// Round-3 lesson: direct-from-L2 act (no LDS) regressed 47us — 128 dependent
// VMEM ops/wave vs 8 merged global_load_lds. LDS staging stays.
// Round-4 theory: timed runs are weight-COLD (fills evict L3) -> latency-
// bound; r2's VGPR=116 sat in the 4-waves/SIMD band (occupancy halves at
// VGPR=64/128/256). This version dives under the 64-VGPR cliff:
//   * KS=16: per-wave weight slice = 4 nt dwordx4 = 16 VGPR
//   * P=4:   val[16] = 16 VGPR; LDS = 4KB/block; act staging = ONE
//            full-row global_load_lds per wave per pass (1KB/wave-instr)
//   * __launch_bounds__(256,8): 8 waves/SIMD = 32 waves/CU, 8 resident
//     blocks whose load bursts stagger instead of convoying on one barrier
//   * butterfly: 15 shfls + 2 cross-group adds for all 16 (row,pair) sums
// Weights still read exactly once (held in regs across passes).
// ---------------------------------------------------------------------------
__global__ __launch_bounds__(256, 8) void moe_mlp2(
    const float* __restrict__ act, const float* __restrict__ ew,
    const float* __restrict__ W, float* __restrict__ out,
    const int* __restrict__ cnt, const int* __restrict__ lists)
{
    __shared__ float sact[P][KH];   // 4 x 256 x 4B = 4 KB

    const int bid = blockIdx.x;
    const int e   = bid >> 10;                // 1024 blocks per expert
    const int n   = cnt[e];
    if (n == 0) return;
    const int ct   = (bid >> 4) & 63;         // 64 row-tiles
    const int ks   = bid & (KS - 1);          // 16 K-slices
    const int lane = threadIdx.x & 63;
    const int wave = threadIdx.x >> 6;
    const int row0 = ct * RPB + wave * 4;

    // --- weight slice prefetch: 4 nt dwordx4 per lane (1KB per wave-row),
    //     issued back-to-back; drained by the first staging barrier ---
    const v4f* __restrict__ Wb =
        (const v4f*)(W + (size_t)(e * CC + row0) * KK + ks * KH);
    v4f w[4];
#pragma unroll
    for (int r = 0; r < 4; r++)
        w[r] = __builtin_nontemporal_load(Wb + (size_t)r * (KK / 4) + lane);

    for (int g = 0; g < n; g += P) {
        const int np = min(P, n - g);
        if (g) __syncthreads();   // prev pass's reads done before re-stage

        // --- async global->LDS staging: wave v stages pair v's full row.
        //     One wave-instr = 64 lanes x 16B = 1KB = KH floats. lds dest
        //     is wave-uniform (HW rule); per-lane offset in global src. ---
        if (wave < np) {
            int pr = lists[e * 128 + g + wave];
            const float* gsrc =
                act + (size_t)pr * KK + ks * KH + lane * 4;
            __builtin_amdgcn_global_load_lds(
                (const __attribute__((address_space(1))) void*)gsrc,
                (__attribute__((address_space(3))) void*)&sact[wave][0],
                16, 0, 0);
        }
        __syncthreads();   // drains staging (and, first pass, the weights)

        // --- accumulate: val[(p<<2)|r] = lane's partial for (pair p, row r)
        float val[16];
#pragma unroll
        for (int i = 0; i < 16; i++) val[i] = 0.f;

        const int fb = lane * 4;   // this lane's 4 floats of the slice
#pragma unroll
        for (int p = 0; p < P; p++) {
            if (p < np) {                       // wave-uniform guard
                const v4f a = *(const v4f*)&sact[p][fb];
#pragma unroll
                for (int r = 0; r < 4; r++)
                    val[(p << 2) | r] += w[r].x * a.x + w[r].y * a.y +
                                         w[r].z * a.z + w[r].w * a.w;
            }
        }

        // --- butterfly: 4 value-halving steps (15 shfls) reduce within each
        //     16-lane group; after them, slot 0 of lane l holds the 16-lane
        //     partial of value (l&15). Two cross-group adds finish the
        //     64-lane sum. Dead pairs (>=np) are exact zeros. ---
#pragma unroll
        for (int st = 0; st < 4; st++) {
            const int m = 1 << st;
            const bool hi = (lane & m) != 0;
#pragma unroll
            for (int i = 0; i < 16; i += 2 * m) {
                float send = hi ? val[i] : val[i + m];
                float recv = __shfl_xor(send, m, 64);
                val[i] = (hi ? val[i + m] : val[i]) + recv;
            }
        }
        float v0 = val[0];
        v0 += __shfl_xor(v0, 16, 64);
        v0 += __shfl_xor(v0, 32, 64);

        // lane l<16 owns (pair = l>>2, row = row0 + (l&3))
        const int p = lane >> 2;
        if (lane < 16 && p < np) {
            int pr = lists[e * 128 + g + p];
            atomicAdd(out + (size_t)(pr >> 1) * CC + row0 + (lane & 3),
                      ew[pr] * v0);
        }
    }
}

extern "C" void kernel_launch(void* const* d_in, const int* in_sizes, int n_in,
                              void* d_out, int out_size, void* d_ws, size_t ws_size,
                              hipStream_t stream) {
    const float* act   = (const float*)d_in[0];   // [B, TOPK, K]
    const int*   idx   = (const int*)d_in[1];     // [B, TOPK]
    const float* ew    = (const float*)d_in[2];   // [B, TOPK]
    const float* W     = (const float*)d_in[3];   // [E, C, K]
    const float* bias  = (const float*)d_in[4];   // [E, C]
    const float* resid = (const float*)d_in[5];   // [B, C]
    float* out = (float*)d_out;

    int* cnt   = (int*)d_ws;          // 16 ints
    int* lists = (int*)d_ws + 64;     // 16 * 128 ints, 256B-aligned offset

    route_init<<<1 + (BB * CC) / 256, 256, 0, stream>>>(
        idx, ew, bias, resid, out, cnt, lists);
    moe_mlp2<<<EE * 64 * KS, 256, 0, stream>>>(
        act, ew, W, out, cnt, lists);
}

// Round 5
// 354.654 us; speedup vs baseline: 1.8991x; 1.8991x over previous
//
#include <hip/hip_runtime.h>

// Problem constants (from reference): B=64, TOPK=2, E=16, C=1024, K=4096
#define BB    64
#define TOPK  2
#define EE    16
#define CC    1024
#define KK    4096

constexpr int RPB = 16;            // weight rows per block (4 per wave)
constexpr int P   = 16;            // max (token,slot) pairs per pass
constexpr int KS  = 8;             // K-split (partials to workspace)
constexpr int KH  = KK / KS;       // floats per K-slice (=512)
constexpr int NW  = KH / 4 / 64;   // float4 windows per slice per lane (=2)

typedef float v4f __attribute__((ext_vector_type(4)));

// ---------------------------------------------------------------------------
// Kernel 1: grid = E * 64 * KS = 8192 one-shot blocks (r2 skeleton — best
// measured config at 367.7us total).
//
// Round-4 lesson: KS=16/P=4 exploded atomic RMW traffic (WRITE 32->720 MB)
// and per-pass overhead; occupancy was NOT the binding constraint. Revert.
// Round-5 changes, keeping the r2 hot loop byte-for-byte:
//   * NO atomics: the butterfly already finishes each (pair,row) sum in a
//     single lane -> plain store to partial[pair][ks][row] (4 MB ws, each
//     slot written exactly once). Replaces 1M coherence-point RMWs.
//   * NO route_init dependency: each block builds its expert list from idx
//     (512 B, L2-broadcast) with two cheap barriers BEFORE any heavy load
//     is issued. moe_mlp2 launches at t=0.
// Weights still read exactly once, held in registers across passes.
// ---------------------------------------------------------------------------
__global__ __launch_bounds__(256, 4) void moe_mlp2(
    const float* __restrict__ act, const int* __restrict__ idx,
    const float* __restrict__ W, float* __restrict__ partial)
{
    __shared__ float sact[P][KH];      // 16 x 512 x 4B = 32 KB
    __shared__ int   slist[BB * TOPK];
    __shared__ int   scnt;

    const int bid  = blockIdx.x;
    const int e    = bid >> 9;                // 512 blocks per expert
    const int ct   = (bid >> 3) & 63;         // 64 row-tiles
    const int ks   = bid & (KS - 1);          // 8 K-slices
    const int tid  = threadIdx.x;
    const int lane = tid & 63;
    const int wave = tid >> 6;
    const int row0 = ct * RPB + wave * 4;

    // --- in-block routing (replaces route_init): both barriers happen
    //     before the weight burst, so nothing heavy gets drained by them ---
    if (tid == 0) scnt = 0;
    __syncthreads();
    if (tid < BB * TOPK && idx[tid] == e) {
        int pos = atomicAdd(&scnt, 1);       // LDS atomic; order irrelevant
        slist[pos] = tid;                    // pair id = b*TOPK + slot
    }
    __syncthreads();
    const int n = scnt;
    if (n == 0) return;

    // --- weight slice prefetch: 8 nt dwordx4 per lane, issued back-to-back;
    //     drained by the staging barrier below (one-shot block: wanted) ---
    const v4f* __restrict__ Wb =
        (const v4f*)(W + (size_t)(e * CC + row0) * KK + ks * KH);
    v4f w[4][NW];
#pragma unroll
    for (int r = 0; r < 4; r++)
#pragma unroll
        for (int kw = 0; kw < NW; kw++)
            w[r][kw] = __builtin_nontemporal_load(
                Wb + (size_t)r * (KK / 4) + kw * 64 + lane);

    for (int g = 0; g < n; g += P) {
        const int np = min(P, n - g);
        if (g) __syncthreads();   // prev pass's reads done before re-stage

        // --- async global->LDS staging. Half-row granularity: one wave
        //     instr = 64 lanes x 16B = 1 KB = KH/2 floats. lds dest is
        //     wave-uniform base + lane*16 (HW rule); per-lane offset lives
        //     in the global src address. ---
        for (int h = wave; h < 2 * np; h += 4) {
            int pr = slist[g + (h >> 1)];
            const float* gsrc = act + (size_t)pr * KK + ks * KH
                              + (h & 1) * (KH / 2) + lane * 4;
            __builtin_amdgcn_global_load_lds(
                (const __attribute__((address_space(1))) void*)gsrc,
                (__attribute__((address_space(3))) void*)
                    &sact[h >> 1][(h & 1) * (KH / 2)],
                16, 0, 0);
        }
        __syncthreads();   // drains staging AND weight prefetch

        // --- accumulate: val[(p<<2)|r] = lane's partial for (pair p, row r)
        float val[64];
#pragma unroll
        for (int i = 0; i < 64; i++) val[i] = 0.f;

#pragma unroll
        for (int kw = 0; kw < NW; kw++) {
            const int fb = (kw * 64 + lane) * 4;   // float idx within slice
#pragma unroll
            for (int pc = 0; pc < P / 4; pc++) {
                if (pc * 4 < np) {                  // wave-uniform guard
#pragma unroll
                    for (int j = 0; j < 4; j++) {
                        const int p = pc * 4 + j;
                        const v4f a = *(const v4f*)&sact[p][fb];
#pragma unroll
                        for (int r = 0; r < 4; r++)
                            val[(p << 2) | r] +=
                                w[r][kw].x * a.x + w[r][kw].y * a.y +
                                w[r][kw].z * a.z + w[r][kw].w * a.w;
                    }
                }
            }
        }

        // --- butterfly reduction, 63 shfls total. After step s, slot i
        //     (i % 2^(s+1) == 0) holds the 2^(s+1)-lane partial of logical
        //     value (i | (lane & (2^(s+1)-1))). After 6 steps lane l's
        //     val[0] = full 64-lane sum of value l = (pair l>>2, row l&3). ---
#pragma unroll
        for (int s = 0; s < 6; s++) {
            const int m = 1 << s;
            const bool hi = (lane & m) != 0;
#pragma unroll
            for (int i = 0; i < 64; i += 2 * m) {
                float send = hi ? val[i] : val[i + m];
                float recv = __shfl_xor(send, m, 64);
                val[i] = (hi ? val[i + m] : val[i]) + recv;
            }
        }

        // non-atomic partial store: each (pair,ks,row) written exactly once
        const int p = lane >> 2;
        if (p < np) {
            int pr = slist[g + p];
            partial[((size_t)pr * KS + ks) * CC + row0 + (lane & 3)] = val[0];
        }
    }
}

// ---------------------------------------------------------------------------
// Kernel 2: finalize — out = resid + sum_s ew * (bias + sum_ks partial).
// 256 blocks; all reads fully coalesced (consecutive c across lanes); the
// 4 MB partial buffer is L2/IF-hot (just written).
// ---------------------------------------------------------------------------
__global__ __launch_bounds__(256) void finalize(
    const int* __restrict__ idx, const float* __restrict__ ew,
    const float* __restrict__ bias, const float* __restrict__ resid,
    const float* __restrict__ partial, float* __restrict__ out)
{
    const int i = blockIdx.x * 256 + threadIdx.x;   // [0, B*C)
    const int b = i >> 10;                           // C = 1024
    const int c = i & (CC - 1);
    float v = resid[i];
#pragma unroll
    for (int s = 0; s < TOPK; s++) {
        const int pr = b * TOPK + s;
        const int e  = idx[pr];
        float t = bias[e * CC + c];
#pragma unroll
        for (int ks = 0; ks < KS; ks++)
            t += partial[((size_t)pr * KS + ks) * CC + c];
        v += ew[pr] * t;
    }
    out[i] = v;
}

extern "C" void kernel_launch(void* const* d_in, const int* in_sizes, int n_in,
                              void* d_out, int out_size, void* d_ws, size_t ws_size,
                              hipStream_t stream) {
    const float* act   = (const float*)d_in[0];   // [B, TOPK, K]
    const int*   idx   = (const int*)d_in[1];     // [B, TOPK]
    const float* ew    = (const float*)d_in[2];   // [B, TOPK]
    const float* W     = (const float*)d_in[3];   // [E, C, K]
    const float* bias  = (const float*)d_in[4];   // [E, C]
    const float* resid = (const float*)d_in[5];   // [B, C]
    float* out = (float*)d_out;

    float* partial = (float*)d_ws;    // [B*TOPK][KS][C] = 4 MB

    moe_mlp2<<<EE * 64 * KS, 256, 0, stream>>>(act, idx, W, partial);
    finalize<<<(BB * CC) / 256, 256, 0, stream>>>(
        idx, ew, bias, resid, partial, out);
}

// Round 7
// 351.310 us; speedup vs baseline: 1.9172x; 1.0095x over previous
//
#include <hip/hip_runtime.h>

// Problem constants (from reference): B=64, TOPK=2, E=16, C=1024, K=4096
#define BB    64
#define TOPK  2
#define EE    16
#define CC    1024
#define KK    4096

constexpr int RPB = 16;            // weight rows per block (4 per wave)
constexpr int P   = 16;            // max (token,slot) pairs per pass
constexpr int KS  = 8;             // K-split (partials to workspace)
constexpr int KH  = KK / KS;       // floats per K-slice (=512)
constexpr int NW  = KH / 4 / 64;   // float4 windows per slice per lane (=2)

typedef float v4f __attribute__((ext_vector_type(4)));

// ---------------------------------------------------------------------------
// Kernel 1: grid = E * 64 * KS = 8192 one-shot blocks (r5 skeleton, best
// at 354.7us total; no atomics, no route_init dependency).
//
// Round-6 change (T4 counted-vmcnt, one-shot analog): the old
// __syncthreads() after staging lowered to s_waitcnt vmcnt(0)+barrier,
// draining all 8 weight loads (~3200 BW-bound cycles) before any FMA.
// New first-pass order:
//   1. issue act staging (global_load_lds)      <- oldest in vmcnt queue
//   2. issue 8 weight nt loads, kw-major        <- newest
//   3. asm s_waitcnt vmcnt(8): my staging done, weights still in flight
//   4. raw s_barrier: all waves' staging done -> LDS valid
//   5. FMA loop: compiler's own incremental vmcnt(N) releases each kw
//      batch as it lands; compute overlaps the weight arrival tail.
// sched_barrier(0) fences pin the issue order (it is load-bearing for the
// vmcnt count). Rare multi-pass path (n>16) keeps plain __syncthreads().
// Butterfly fast path: np<=8 (the common case, E[n]=8) uses 32 shfls.
// (Round 6 bench was an infra failure — this is an unchanged resubmit.)
// ---------------------------------------------------------------------------
__global__ __launch_bounds__(256, 4) void moe_mlp2(
    const float* __restrict__ act, const int* __restrict__ idx,
    const float* __restrict__ W, float* __restrict__ partial)
{
    __shared__ float sact[P][KH];      // 16 x 512 x 4B = 32 KB
    __shared__ int   slist[BB * TOPK];
    __shared__ int   scnt;

    const int bid  = blockIdx.x;
    const int e    = bid >> 9;                // 512 blocks per expert
    const int ct   = (bid >> 3) & 63;         // 64 row-tiles
    const int ks   = bid & (KS - 1);          // 8 K-slices
    const int tid  = threadIdx.x;
    const int lane = tid & 63;
    const int wave = tid >> 6;
    const int row0 = ct * RPB + wave * 4;

    // --- in-block routing: both barriers happen before any heavy load ---
    if (tid == 0) scnt = 0;
    __syncthreads();
    if (tid < BB * TOPK && idx[tid] == e) {
        int pos = atomicAdd(&scnt, 1);       // LDS atomic; order irrelevant
        slist[pos] = tid;                    // pair id = b*TOPK + slot
    }
    __syncthreads();
    const int n = scnt;
    if (n == 0) return;

    const v4f* __restrict__ Wb =
        (const v4f*)(W + (size_t)(e * CC + row0) * KK + ks * KH);

    // --- async global->LDS act staging for one pass. Half-row granularity:
    //     one wave-instr = 64 lanes x 16B = 1 KB = KH/2 floats. lds dest is
    //     wave-uniform base + lane*16 (HW rule); per-lane offset lives in
    //     the global src address. ---
    auto STAGE = [&](int g, int np) {
        for (int h = wave; h < 2 * np; h += 4) {
            int pr = slist[g + (h >> 1)];
            const float* gsrc = act + (size_t)pr * KK + ks * KH
                              + (h & 1) * (KH / 2) + lane * 4;
            __builtin_amdgcn_global_load_lds(
                (const __attribute__((address_space(1))) void*)gsrc,
                (__attribute__((address_space(3))) void*)
                    &sact[h >> 1][(h & 1) * (KH / 2)],
                16, 0, 0);
        }
    };

    // --- first pass: staging FIRST (oldest), then weights (newest), then
    //     counted wait. vmcnt(8) == "everything except my 8 weight loads". ---
    v4f w[NW][4];   // kw-major: issue order == use order
    {
        const int np0 = min(P, n);
        STAGE(0, np0);
        __builtin_amdgcn_sched_barrier(0);   // pin: staging before weights
#pragma unroll
        for (int kw = 0; kw < NW; kw++)
#pragma unroll
            for (int r = 0; r < 4; r++)
                w[kw][r] = __builtin_nontemporal_load(
                    Wb + (size_t)r * (KK / 4) + kw * 64 + lane);
        __builtin_amdgcn_sched_barrier(0);   // pin: weights before wait
        asm volatile("s_waitcnt vmcnt(8)" ::: "memory");
        __builtin_amdgcn_sched_barrier(0);
        __builtin_amdgcn_s_barrier();        // all waves' staging visible
        __builtin_amdgcn_sched_barrier(0);   // no ds_read hoisted above
    }

    for (int g = 0; g < n; g += P) {
        const int np = min(P, n - g);
        if (g) {   // rare (n>16): safe full-drain restage
            __syncthreads();
            STAGE(g, np);
            __syncthreads();
        }

        // --- accumulate: val[(p<<2)|r] = lane's partial for (pair p, row r)
        float val[64];
#pragma unroll
        for (int i = 0; i < 64; i++) val[i] = 0.f;

#pragma unroll
        for (int kw = 0; kw < NW; kw++) {
            const int fb = (kw * 64 + lane) * 4;   // float idx within slice
#pragma unroll
            for (int pc = 0; pc < P / 4; pc++) {
                if (pc * 4 < np) {                  // wave-uniform guard
#pragma unroll
                    for (int j = 0; j < 4; j++) {
                        const int p = pc * 4 + j;
                        const v4f a = *(const v4f*)&sact[p][fb];
#pragma unroll
                        for (int r = 0; r < 4; r++)
                            val[(p << 2) | r] +=
                                w[kw][r].x * a.x + w[kw][r].y * a.y +
                                w[kw][r].z * a.z + w[kw][r].w * a.w;
                    }
                }
            }
        }

        // --- butterfly reduction. Invariant: after step s, slot i
        //     (i % 2^(s+1) == 0) holds the 2^(s+1)-lane partial of logical
        //     value (i | (lane & (2^(s+1)-1))). Dead pairs are exact zeros.
        if (np <= 8) {
            // 32 live slots: 5 steps within 32-lane halves (31 shfls) +
            // one cross-half add. Lanes l and l+32 both end with value l&31.
#pragma unroll
            for (int s = 0; s < 5; s++) {
                const int m = 1 << s;
                const bool hi = (lane & m) != 0;
#pragma unroll
                for (int i = 0; i < 32; i += 2 * m) {
                    float send = hi ? val[i] : val[i + m];
                    float recv = __shfl_xor(send, m, 64);
                    val[i] = (hi ? val[i + m] : val[i]) + recv;
                }
            }
            float v0 = val[0];
            v0 += __shfl_xor(v0, 32, 64);
            const int p = (lane & 31) >> 2;
            if (lane < 32 && p < np) {
                int pr = slist[g + p];
                partial[((size_t)pr * KS + ks) * CC + row0 + (lane & 3)] = v0;
            }
        } else {
            // full 64-slot butterfly: 6 steps, 63 shfls
#pragma unroll
            for (int s = 0; s < 6; s++) {
                const int m = 1 << s;
                const bool hi = (lane & m) != 0;
#pragma unroll
                for (int i = 0; i < 64; i += 2 * m) {
                    float send = hi ? val[i] : val[i + m];
                    float recv = __shfl_xor(send, m, 64);
                    val[i] = (hi ? val[i + m] : val[i]) + recv;
                }
            }
            const int p = lane >> 2;
            if (p < np) {
                int pr = slist[g + p];
                partial[((size_t)pr * KS + ks) * CC + row0 + (lane & 3)] =
                    val[0];
            }
        }
    }
}

// ---------------------------------------------------------------------------
// Kernel 2: finalize — out = resid + sum_s ew * (bias + sum_ks partial).
// 256 blocks; all reads fully coalesced; partial (4 MB) is L2/IF-hot.
// ---------------------------------------------------------------------------
__global__ __launch_bounds__(256) void finalize(
    const int* __restrict__ idx, const float* __restrict__ ew,
    const float* __restrict__ bias, const float* __restrict__ resid,
    const float* __restrict__ partial, float* __restrict__ out)
{
    const int i = blockIdx.x * 256 + threadIdx.x;   // [0, B*C)
    const int b = i >> 10;                           // C = 1024
    const int c = i & (CC - 1);
    float v = resid[i];
#pragma unroll
    for (int s = 0; s < TOPK; s++) {
        const int pr = b * TOPK + s;
        const int e  = idx[pr];
        float t = bias[e * CC + c];
#pragma unroll
        for (int ks = 0; ks < KS; ks++)
            t += partial[((size_t)pr * KS + ks) * CC + c];
        v += ew[pr] * t;
    }
    out[i] = v;
}

extern "C" void kernel_launch(void* const* d_in, const int* in_sizes, int n_in,
                              void* d_out, int out_size, void* d_ws, size_t ws_size,
                              hipStream_t stream) {
    const float* act   = (const float*)d_in[0];   // [B, TOPK, K]
    const int*   idx   = (const int*)d_in[1];     // [B, TOPK]
    const float* ew    = (const float*)d_in[2];   // [B, TOPK]
    const float* W     = (const float*)d_in[3];   // [E, C, K]
    const float* bias  = (const float*)d_in[4];   // [E, C]
    const float* resid = (const float*)d_in[5];   // [B, C]
    float* out = (float*)d_out;

    float* partial = (float*)d_ws;    // [B*TOPK][KS][C] = 4 MB

    moe_mlp2<<<EE * 64 * KS, 256, 0, stream>>>(act, idx, W, partial);
    finalize<<<(BB * CC) / 256, 256, 0, stream>>>(
        idx, ew, bias, resid, partial, out);
}